// Round 7
// baseline (179.737 us; speedup 1.0000x reference)
//
#include <hip/hip_runtime.h>
#include <cstdint>

// CTC batch cost, scaled linear-domain forward. R6/R7: NO LDS AT ALL.
// Lane i owns extended states {2i, 2i+1}; a2 track duplicates state 2i+2
// (lane63's a2 = state 128). Cross-lane dep = one DPP wave_shr:1 per step.
// Each lane gathers only its own two columns (lab_i, blank=95) directly from
// global memory; rows are 384B so the 64-lane gather coalesces to ~6 line
// transactions (exactly the needed lines -> HBM traffic ~= 100MB ideal).
// 4-slot register FIFO (issue group g+3 before computing group g) keeps ~48
// loads in flight; sched_barrier(0) pins issue blocks so loads can't sink.
// Rescale (exact power-of-2) every 16 steps, target 2^96.
// (R7 = R6 resubmitted after broker timeout; no logic change.)

constexpr int BB = 256;
constexpr int TT = 1024;
constexpr int CC = 96;
constexpr int LL = 64;
constexpr int G  = 8;          // rows per group
constexpr int NG = TT / G;     // 128 groups
constexpr int SL = 4;          // register FIFO slots
#define EPSF 1e-7f

__device__ __forceinline__ float wf_shr1_f(float v) {
  // whole-wave shift up by 1 lane; lane 0 receives 0.0f (identity here)
  int r = __builtin_amdgcn_update_dpp(0, __float_as_int(v), 0x138 /*WAVE_SHR1*/, 0xF, 0xF, false);
  return __int_as_float(r);
}

template <int CTRL>
__device__ __forceinline__ float dpp_max(float v) {
  int r = __builtin_amdgcn_update_dpp(__float_as_int(v), __float_as_int(v), CTRL, 0xF, 0xF, false);
  return fmaxf(v, __int_as_float(r));
}

__global__ void __launch_bounds__(64, 1)
ctc_fwd(const int* __restrict__ y_true, const float* __restrict__ y_pred,
        float* __restrict__ out) {
  const int b    = blockIdx.x;
  const int lane = threadIdx.x;

  const int lab  = y_true[b * LL + lane];                 // label for state 2*lane+1
  const int labp = __builtin_amdgcn_update_dpp(-1, lab, 0x138, 0xF, 0xF, false);
  const float mskip = (lane > 0 && lab != labp) ? 1.0f : 0.0f;

  const float* __restrict__ p = y_pred + (size_t)b * (TT * CC);

  float Pl[SL][G], Pb[SL][G];   // statically indexed -> stays in VGPRs

  // prologue: issue groups 0..2 into slots 0..2
#pragma unroll
  for (int g = 0; g < SL - 1; ++g) {
    const float* q = p + g * (G * CC);
#pragma unroll
    for (int u = 0; u < G; ++u) {
      Pl[g][u] = q[u * CC + lab];
      Pb[g][u] = q[u * CC + (CC - 1)];
    }
  }

  float a0 = (lane == 0) ? 1.0f : 0.0f;
  float a1 = 0.0f;
  float a2 = 0.0f;
  int   scale = 0;   // exact sum of power-of-2 rescale exponents

#define ISSUE(gidx, slot) do {                                         \
    const float* q = p + (gidx) * (G * CC);                            \
    _Pragma("unroll")                                                  \
    for (int u = 0; u < G; ++u) {                                      \
      Pl[slot][u] = q[u * CC + lab];                                   \
      Pb[slot][u] = q[u * CC + (CC - 1)];                              \
    }                                                                  \
    __builtin_amdgcn_sched_barrier(0);                                 \
  } while (0)

#define STEP8(slot) do {                                               \
    _Pragma("unroll")                                                  \
    for (int u = 0; u < G; ++u) {                                      \
      const float PL  = Pl[slot][u] + EPSF;                            \
      const float PB  = Pb[slot][u] + EPSF;                            \
      const float a1p = wf_shr1_f(a1);                /* alpha[2i-1] */\
      const float na0 = (a0 + a1p) * PB;              /* state 2i    */\
      const float na2 = (a2 + a1) * PB;               /* state 2i+2  */\
      const float na1 = fmaf(a1p, mskip, a1 + a0) * PL; /* 2i+1 */     \
      a0 = na0; a1 = na1; a2 = na2;                                    \
    }                                                                  \
  } while (0)

#define RESCALE do {                                                   \
    float m = fmaxf(fmaxf(a0, a1), a2);                                \
    m = dpp_max<0x111>(m);   /* row_shr:1  */                          \
    m = dpp_max<0x112>(m);   /* row_shr:2  */                          \
    m = dpp_max<0x114>(m);   /* row_shr:4  */                          \
    m = dpp_max<0x118>(m);   /* row_shr:8  */                          \
    m = dpp_max<0x142>(m);   /* row_bcast:15 */                        \
    m = dpp_max<0x143>(m);   /* row_bcast:31 -> lane 63 = wave max */  \
    const int mb = __builtin_amdgcn_readlane(__float_as_int(m), 63);   \
    const int k  = 223 - ((mb >> 23) & 0xFF);  /* max -> ~2^96 */      \
    scale += k;                                                        \
    a0 = ldexpf(a0, k); a1 = ldexpf(a1, k); a2 = ldexpf(a2, k);        \
  } while (0)

#pragma unroll 1
  for (int it = 0; it < NG / SL - 1; ++it) {   // groups 0..123
    const int g0 = it * SL;
    ISSUE(g0 + 3, 3); STEP8(0);
    ISSUE(g0 + 4, 0); STEP8(1); RESCALE;
    ISSUE(g0 + 5, 1); STEP8(2);
    ISSUE(g0 + 6, 2); STEP8(3); RESCALE;
  }
  // peeled tail: groups 124..127 (only group 127 left to issue)
  ISSUE(127, 3); STEP8(0);
  STEP8(1); RESCALE;
  STEP8(2);
  STEP8(3); RESCALE;

#undef ISSUE
#undef STEP8
#undef RESCALE

  if (lane == 63) {
    const float s = a1 + a2;  // alpha[127] + alpha[128] (scaled)
    out[b] = 0.693147180559945f * ((float)scale - log2f(s));
  }
}

extern "C" void kernel_launch(void* const* d_in, const int* in_sizes, int n_in,
                              void* d_out, int out_size, void* d_ws, size_t ws_size,
                              hipStream_t stream) {
  (void)in_sizes; (void)n_in; (void)d_ws; (void)ws_size; (void)out_size;
  const int*   y_true = (const int*)d_in[0];
  const float* y_pred = (const float*)d_in[1];
  float*       out    = (float*)d_out;
  ctc_fwd<<<BB, 64, 0, stream>>>(y_true, y_pred, out);
}

// Round 9
// 155.142 us; speedup vs baseline: 1.1585x; 1.1585x over previous
//
#include <hip/hip_runtime.h>
#include <cstdint>

// CTC batch cost, scaled linear-domain forward. R8/R9: inline-asm register FIFO.
// R7 evidence: VGPR_Count=40 proved the compiler collapsed the C-level
// 4-slot FIFO (sank loads to uses despite sched_barrier) -> serial ~400cy
// latency per 8-row group, 172 cy/step, 73us. Fix: loads are asm volatile
// global_load_dword into asm-output VGPRs (compiler cannot sink/collapse),
// completion via hand-counted s_waitcnt vmcnt(32/16/0) + sched_barrier(0)
// (rule #18). 4 slots x 16 loads; issue group g+3 after waiting group g ->
// 48 loads in flight, lookahead ~3 groups (~550cy) > L2/L3 latency.
// Lane i owns states {2i,2i+1}; a2 duplicates 2i+2 (lane63: state 128).
// Cross-lane dep = one DPP wave_shr:1 per step. Rescale 2^k every 16 steps.
// (R9 = R8 resubmitted after container-infra failure; no logic change.)

constexpr int BB = 256;
constexpr int TT = 1024;
constexpr int CC = 96;
constexpr int LL = 64;
#define EPSF 1e-7f

__device__ __forceinline__ float wf_shr1_f(float v) {
  int r = __builtin_amdgcn_update_dpp(0, __float_as_int(v), 0x138 /*WAVE_SHR1*/, 0xF, 0xF, false);
  return __int_as_float(r);
}

template <int CTRL>
__device__ __forceinline__ float dpp_max(float v) {
  int r = __builtin_amdgcn_update_dpp(__float_as_int(v), __float_as_int(v), CTRL, 0xF, 0xF, false);
  return fmaxf(v, __int_as_float(r));
}

// one per-lane gather load, compile-time byte offset, result pinned in a VGPR
#define GL(dst, ptr, OFF)                                              \
  asm volatile("global_load_dword %0, %1, off offset:" #OFF            \
               : "=&v"(dst) : "v"(ptr))

// issue one 8-row group into FIFO slot s: 8 label-col + 8 blank-col loads,
// then advance the rolling base pointers by 8 rows (768 floats = 3072 B)
#define ISSUE(s) do {                                                  \
    GL(Pl[s][0], ql, 0);    GL(Pl[s][1], ql, 384);                     \
    GL(Pl[s][2], ql, 768);  GL(Pl[s][3], ql, 1152);                    \
    GL(Pl[s][4], ql, 1536); GL(Pl[s][5], ql, 1920);                    \
    GL(Pl[s][6], ql, 2304); GL(Pl[s][7], ql, 2688);                    \
    GL(Pb[s][0], qb, 0);    GL(Pb[s][1], qb, 384);                     \
    GL(Pb[s][2], qb, 768);  GL(Pb[s][3], qb, 1152);                    \
    GL(Pb[s][4], qb, 1536); GL(Pb[s][5], qb, 1920);                    \
    GL(Pb[s][6], qb, 2304); GL(Pb[s][7], qb, 2688);                    \
    ql += 8 * CC; qb += 8 * CC;                                        \
  } while (0)

// wait until <= N vmem ops outstanding, then fence the scheduler (rule #18)
#define WAITN(N) do {                                                  \
    asm volatile("s_waitcnt vmcnt(" #N ")" ::: "memory");              \
    __builtin_amdgcn_sched_barrier(0);                                 \
  } while (0)

#define STEP8(s) do {                                                  \
    _Pragma("unroll")                                                  \
    for (int u = 0; u < 8; ++u) {                                      \
      const float PL  = Pl[s][u] + EPSF;                               \
      const float PB  = Pb[s][u] + EPSF;                               \
      const float a1p = wf_shr1_f(a1);                /* alpha[2i-1] */\
      const float na0 = (a0 + a1p) * PB;              /* state 2i    */\
      const float na2 = (a2 + a1) * PB;               /* state 2i+2  */\
      const float na1 = fmaf(a1p, mskip, a1 + a0) * PL; /* 2i+1 */     \
      a0 = na0; a1 = na1; a2 = na2;                                    \
    }                                                                  \
  } while (0)

#define RESCALE do {                                                   \
    float m = fmaxf(fmaxf(a0, a1), a2);                                \
    m = dpp_max<0x111>(m);   /* row_shr:1  */                          \
    m = dpp_max<0x112>(m);   /* row_shr:2  */                          \
    m = dpp_max<0x114>(m);   /* row_shr:4  */                          \
    m = dpp_max<0x118>(m);   /* row_shr:8  */                          \
    m = dpp_max<0x142>(m);   /* row_bcast:15 */                        \
    m = dpp_max<0x143>(m);   /* row_bcast:31 -> lane63 = wave max */   \
    const int mb = __builtin_amdgcn_readlane(__float_as_int(m), 63);   \
    const int k  = 223 - ((mb >> 23) & 0xFF);  /* max -> ~2^96 */      \
    scale += k;                                                        \
    a0 = ldexpf(a0, k); a1 = ldexpf(a1, k); a2 = ldexpf(a2, k);        \
  } while (0)

__global__ void __launch_bounds__(64, 1)
ctc_fwd(const int* __restrict__ y_true, const float* __restrict__ y_pred,
        float* __restrict__ out) {
  const int b    = blockIdx.x;
  const int lane = threadIdx.x;

  const int lab  = y_true[b * LL + lane];                 // label for state 2*lane+1
  const int labp = __builtin_amdgcn_update_dpp(-1, lab, 0x138, 0xF, 0xF, false);
  const float mskip = (lane > 0 && lab != labp) ? 1.0f : 0.0f;

  const float* __restrict__ p = y_pred + (size_t)b * (TT * CC);
  const float* ql = p + lab;        // rolling base, label column
  const float* qb = p + (CC - 1);   // rolling base, blank column

  float Pl[4][8], Pb[4][8];         // asm-pinned FIFO (all indices literal)

  float a0 = (lane == 0) ? 1.0f : 0.0f;
  float a1 = 0.0f;
  float a2 = 0.0f;
  int   scale = 0;

  // prologue: groups 0,1,2 -> slots 0,1,2 (48 loads in flight)
  ISSUE(0); ISSUE(1); ISSUE(2);

#pragma unroll 1
  for (int it = 0; it < 31; ++it) {      // groups 4*it .. 4*it+3
    WAITN(32); ISSUE(3); STEP8(0);       // wait g, issue g+3
    WAITN(32); ISSUE(0); STEP8(1); RESCALE;
    WAITN(32); ISSUE(1); STEP8(2);
    WAITN(32); ISSUE(2); STEP8(3); RESCALE;
  }
  // final body: groups 124..127; only group 127 left to issue
  WAITN(32); ISSUE(3); STEP8(0);         // g=124, issues 127
  WAITN(32);           STEP8(1); RESCALE; // g=125
  WAITN(16);           STEP8(2);          // g=126
  WAITN(0);            STEP8(3); RESCALE; // g=127

  if (lane == 63) {
    const float s = a1 + a2;  // alpha[127] + alpha[128] (scaled)
    out[b] = 0.693147180559945f * ((float)scale - log2f(s));
  }
}

extern "C" void kernel_launch(void* const* d_in, const int* in_sizes, int n_in,
                              void* d_out, int out_size, void* d_ws, size_t ws_size,
                              hipStream_t stream) {
  (void)in_sizes; (void)n_in; (void)d_ws; (void)ws_size; (void)out_size;
  const int*   y_true = (const int*)d_in[0];
  const float* y_pred = (const float*)d_in[1];
  float*       out    = (float*)d_out;
  ctc_fwd<<<BB, 64, 0, stream>>>(y_true, y_pred, out);
}